// Round 1
// baseline (107.853 us; speedup 1.0000x reference)
//
#include <hip/hip_runtime.h>

// RNNLayer: y[t][bs] = sum_{d=0}^{t} w[d] * x[t-d][bs],  w[d] = sum_j b[j]*c[j]*a[j]^d
// (diagonal linear RNN with d_in=1 collapses to a causal Toeplitz conv)

#define SEQ 784
#define BSZ 256
#define DH  512
#define TT  8   // output rows per block in conv kernel

// ---- Kernel A: w[d] = sum_j (b[j]*c[j]) * a[j]^d, one block per d ----
__global__ __launch_bounds__(64) void rnn_wkern(const float* __restrict__ a,
                                                const float* __restrict__ b,
                                                const float* __restrict__ c,
                                                float* __restrict__ w) {
    const int d    = blockIdx.x;
    const int lane = threadIdx.x;
    const float fd = (float)d;

    float sum = 0.f;
#pragma unroll
    for (int m = 0; m < DH / 64; ++m) {
        const int j = lane + m * 64;
        const float av = a[j];
        const float cb = b[j] * c[j];
        // a in [0.999, 1.001): ln(1+e) series on e = a-1 (subtraction exact here)
        const float e = av - 1.0f;
        const float lna = e * (1.0f + e * (-0.5f + e * (0.33333333f + e * (-0.25f))));
        sum += cb * __expf(fd * lna);
    }
    // 64-lane butterfly reduce
#pragma unroll
    for (int off = 32; off >= 1; off >>= 1)
        sum += __shfl_xor(sum, off, 64);
    if (lane == 0) w[d] = sum;
}

// ---- Kernel B: causal conv. Block = 256 threads (one per bs column), TT rows ----
__global__ __launch_bounds__(256) void rnn_conv(const float* __restrict__ x,
                                                const float* __restrict__ w,
                                                float* __restrict__ y) {
    __shared__ float wl[SEQ];
    const int tid = threadIdx.x;
    for (int i = tid; i < SEQ; i += 256) wl[i] = w[i];
    __syncthreads();

    const int t0 = blockIdx.x * TT;
    const int bs = tid;

    float acc[TT];
    float buf[TT];  // circular window: at step d, buf[(i-d)&(TT-1)] == x[t0+i-d][bs]
#pragma unroll
    for (int i = 0; i < TT; ++i) {
        acc[i] = 0.f;
        buf[i] = x[(t0 + i) * BSZ + bs];  // d=0 window, rows t0..t0+TT-1 all valid
    }

    for (int D = 0; D < SEQ; D += TT) {
#pragma unroll
        for (int k = 0; k < TT; ++k) {
            const int d = D + k;           // D % TT == 0, so (i-d)&7 == (i-k)&7
            const float wv = wl[d];
#pragma unroll
            for (int i = 0; i < TT; ++i)
                acc[i] += wv * buf[(i - k) & (TT - 1)];
            // retire row t0+TT-1-d, bring in row t0-d-1 (zero if out of range)
            const int rnew = t0 - d - 1;   // uniform across block
            float nv = 0.f;
            if (rnew >= 0) nv = x[rnew * BSZ + bs];
            buf[(TT - 1 - k) & (TT - 1)] = nv;
        }
    }

#pragma unroll
    for (int i = 0; i < TT; ++i)
        y[(t0 + i) * BSZ + bs] = acc[i];
}

extern "C" void kernel_launch(void* const* d_in, const int* in_sizes, int n_in,
                              void* d_out, int out_size, void* d_ws, size_t ws_size,
                              hipStream_t stream) {
    const float* x = (const float*)d_in[0];  // [784, 256, 1]
    const float* a = (const float*)d_in[1];  // [512]
    const float* b = (const float*)d_in[2];  // [1, 512]
    const float* c = (const float*)d_in[3];  // [512, 1]
    float* y = (float*)d_out;                // [784, 256, 1]
    float* w = (float*)d_ws;                 // 784 floats scratch

    rnn_wkern<<<SEQ, 64, 0, stream>>>(a, b, c, w);
    rnn_conv<<<SEQ / TT, 256, 0, stream>>>(x, w, y);
}

// Round 2
// 73.557 us; speedup vs baseline: 1.4663x; 1.4663x over previous
//
#include <hip/hip_runtime.h>

// RNNLayer: y[t][bs] = sum_{d=0}^{t} w[d] * x[t-d][bs],  w[d] = sum_j b[j]*c[j]*a[j]^d
// (diagonal linear RNN with d_in=1 collapses to a causal Toeplitz conv)
// R2: split the d-sum into NCH chunks -> 7x more blocks, 7x shorter serial
// chain per block; partials combined via f32 atomicAdd into zeroed y.

#define SEQ   784
#define BSZ   256
#define DH    512
#define TT    8     // output rows per tile
#define CHUNK 112   // d-steps per block; 112 % 8 == 0 keeps window invariant
#define NCH   7     // 7 * 112 == 784

// ---- Kernel A: w[d] = sum_j (b[j]*c[j]) * a[j]^d, one block per d ----
__global__ __launch_bounds__(64) void rnn_wkern(const float* __restrict__ a,
                                                const float* __restrict__ b,
                                                const float* __restrict__ c,
                                                float* __restrict__ w) {
    const int d    = blockIdx.x;
    const int lane = threadIdx.x;
    const float fd = (float)d;

    float sum = 0.f;
#pragma unroll
    for (int m = 0; m < DH / 64; ++m) {
        const int j = lane + m * 64;
        const float av = a[j];
        const float cb = b[j] * c[j];
        // a in [0.999, 1.001): ln(1+e) series on e = a-1 (subtraction exact here)
        const float e = av - 1.0f;
        const float lna = e * (1.0f + e * (-0.5f + e * (0.33333333f + e * (-0.25f))));
        sum += cb * __expf(fd * lna);
    }
#pragma unroll
    for (int off = 32; off >= 1; off >>= 1)
        sum += __shfl_xor(sum, off, 64);
    if (lane == 0) w[d] = sum;
}

// ---- Kernel B: chunked causal conv. block=(256 bs cols), grid=(98 t-tiles, 7 chunks) ----
__global__ __launch_bounds__(256) void rnn_conv(const float* __restrict__ x,
                                                const float* __restrict__ w,
                                                float* __restrict__ y) {
    const int tb = blockIdx.x;          // t-tile
    const int ch = blockIdx.y;          // d-chunk
    const int t0 = tb * TT;
    const int d0 = ch * CHUNK;
    if (d0 > t0 + TT - 1) return;       // uniform: chunk entirely above diagonal

    __shared__ float wl[CHUNK];
    const int tid = threadIdx.x;
    if (tid < CHUNK) wl[tid] = w[d0 + tid];
    __syncthreads();

    const int bs = tid;

    float acc[TT];
    float buf[TT];  // circular window: at local step kk, buf[(i-kk)&7] == x[t0+i-d0-kk][bs]
#pragma unroll
    for (int i = 0; i < TT; ++i) {
        acc[i] = 0.f;
        const int r = t0 + i - d0;      // <= 783 always
        buf[i] = (r >= 0) ? x[r * BSZ + bs] : 0.f;
    }

    for (int D = 0; D < CHUNK; D += TT) {
#pragma unroll
        for (int k = 0; k < TT; ++k) {
            const int kk = D + k;       // D % 8 == 0, d0 % 8 == 0 -> slot index uses k
            const float wv = wl[kk];
#pragma unroll
            for (int i = 0; i < TT; ++i)
                acc[i] += wv * buf[(i - k) & (TT - 1)];
            const int rnew = t0 - d0 - kk - 1;   // uniform across block
            float nv = 0.f;
            if (rnew >= 0) nv = x[rnew * BSZ + bs];
            buf[(TT - 1 - k) & (TT - 1)] = nv;
        }
    }

#pragma unroll
    for (int i = 0; i < TT; ++i)
        atomicAdd(&y[(t0 + i) * BSZ + bs], acc[i]);
}

extern "C" void kernel_launch(void* const* d_in, const int* in_sizes, int n_in,
                              void* d_out, int out_size, void* d_ws, size_t ws_size,
                              hipStream_t stream) {
    const float* x = (const float*)d_in[0];  // [784, 256, 1]
    const float* a = (const float*)d_in[1];  // [512]
    const float* b = (const float*)d_in[2];  // [1, 512]
    const float* c = (const float*)d_in[3];  // [512, 1]
    float* y = (float*)d_out;                // [784, 256, 1]
    float* w = (float*)d_ws;                 // 784 floats scratch

    hipMemsetAsync(y, 0, SEQ * BSZ * sizeof(float), stream);
    rnn_wkern<<<SEQ, 64, 0, stream>>>(a, b, c, w);
    dim3 grid(SEQ / TT, NCH);
    rnn_conv<<<grid, 256, 0, stream>>>(x, w, y);
}

// Round 3
// 68.930 us; speedup vs baseline: 1.5647x; 1.0671x over previous
//
#include <hip/hip_runtime.h>

// RNNLayer: y[t][bs] = sum_{d=0}^{t} w[d] * x[t-d][bs],  w[d] = sum_j b[j]*c[j]*a[j]^d
// (diagonal linear RNN with d_in=1 collapses to a causal Toeplitz conv)
// R3: CHUNK=56 (14 chunks -> 2x more TLP, half the serial chain);
//     y-zeroing folded into wkern (block d zeroes y row d) -> 2 dispatches total.

#define SEQ   784
#define BSZ   256
#define DH    512
#define TT    8     // output rows per tile
#define CHUNK 56    // d-steps per block; 56 % 8 == 0 keeps window invariant
#define NCH   14    // 14 * 56 == 784

// ---- Kernel A: w[d] = sum_j (b[j]*c[j]) * a[j]^d; also zeroes y row d ----
__global__ __launch_bounds__(64) void rnn_wkern(const float* __restrict__ a,
                                                const float* __restrict__ b,
                                                const float* __restrict__ c,
                                                float* __restrict__ w,
                                                float* __restrict__ y) {
    const int d    = blockIdx.x;
    const int lane = threadIdx.x;

    // zero y row d (256 floats) with float4 stores
    float4 z = make_float4(0.f, 0.f, 0.f, 0.f);
    ((float4*)(y + d * BSZ))[lane] = z;   // lane*16B, 64 lanes = 1024B = 256 floats

    const float fd = (float)d;
    float sum = 0.f;
#pragma unroll
    for (int m = 0; m < DH / 64; ++m) {
        const int j = lane + m * 64;
        const float av = a[j];
        const float cb = b[j] * c[j];
        // a in [0.999, 1.001): ln(1+e) series on e = a-1 (subtraction exact here)
        const float e = av - 1.0f;
        const float lna = e * (1.0f + e * (-0.5f + e * (0.33333333f + e * (-0.25f))));
        sum += cb * __expf(fd * lna);
    }
#pragma unroll
    for (int off = 32; off >= 1; off >>= 1)
        sum += __shfl_xor(sum, off, 64);
    if (lane == 0) w[d] = sum;
}

// ---- Kernel B: chunked causal conv. block=(256 bs cols), grid=(98 t-tiles, 14 chunks) ----
__global__ __launch_bounds__(256) void rnn_conv(const float* __restrict__ x,
                                                const float* __restrict__ w,
                                                float* __restrict__ y) {
    const int tb = blockIdx.x;          // t-tile
    const int ch = blockIdx.y;          // d-chunk
    const int t0 = tb * TT;
    const int d0 = ch * CHUNK;
    if (d0 > t0 + TT - 1) return;       // uniform: chunk entirely above diagonal

    __shared__ float wl[CHUNK];
    const int tid = threadIdx.x;
    if (tid < CHUNK) wl[tid] = w[d0 + tid];
    __syncthreads();

    const int bs = tid;

    float acc[TT];
    float buf[TT];  // circular window: at local step kk, buf[(i-kk)&7] == x[t0+i-d0-kk][bs]
#pragma unroll
    for (int i = 0; i < TT; ++i) {
        acc[i] = 0.f;
        const int r = t0 + i - d0;      // <= 783 always
        buf[i] = (r >= 0) ? x[r * BSZ + bs] : 0.f;
    }

    for (int D = 0; D < CHUNK; D += TT) {
#pragma unroll
        for (int k = 0; k < TT; ++k) {
            const int kk = D + k;       // D % 8 == 0, d0 % 8 == 0 -> slot index uses k
            const float wv = wl[kk];
#pragma unroll
            for (int i = 0; i < TT; ++i)
                acc[i] += wv * buf[(i - k) & (TT - 1)];
            const int rnew = t0 - d0 - kk - 1;   // uniform across block
            float nv = 0.f;
            if (rnew >= 0) nv = x[rnew * BSZ + bs];
            buf[(TT - 1 - k) & (TT - 1)] = nv;
        }
    }

#pragma unroll
    for (int i = 0; i < TT; ++i)
        atomicAdd(&y[(t0 + i) * BSZ + bs], acc[i]);
}

extern "C" void kernel_launch(void* const* d_in, const int* in_sizes, int n_in,
                              void* d_out, int out_size, void* d_ws, size_t ws_size,
                              hipStream_t stream) {
    const float* x = (const float*)d_in[0];  // [784, 256, 1]
    const float* a = (const float*)d_in[1];  // [512]
    const float* b = (const float*)d_in[2];  // [1, 512]
    const float* c = (const float*)d_in[3];  // [512, 1]
    float* y = (float*)d_out;                // [784, 256, 1]
    float* w = (float*)d_ws;                 // 784 floats scratch

    rnn_wkern<<<SEQ, 64, 0, stream>>>(a, b, c, w, y);
    dim3 grid(SEQ / TT, NCH);
    rnn_conv<<<grid, 256, 0, stream>>>(x, w, y);
}